// Round 1
// 1385.192 us; speedup vs baseline: 1.0196x; 1.0196x over previous
//
#include <hip/hip_runtime.h>

// NeuralVoxelHash: out[i] = sum over 3 levels of trilinear-weighted gather of
// hashed voxel-corner features.
//
// inputs (harness delivers integer inputs as int32!):
//   d_in[0] query_points [1000000,3] f32
//   d_in[1] features     [3,4194304,8] f32
//   d_in[2] index_table  [3,5000000] int32  (reference int64, harness -> int)
// output: [1000000,8] f32
//
// Structure (this revision): latency/MLP-oriented.
//  - Phase 1: all 24 index-table gathers issued as one batch (was 3 serial rounds).
//  - Phase 2: per level, all 16 feature float4 loads issued as one batch.
//  - Feature loads + output stores are non-temporal: features (402 MB, zero reuse)
//    must not thrash the L2/L3 space that caches the 60 MB index tables.

constexpr int       BUF   = 5000000;
constexpr long long NFEAT = 4194304;
constexpr int       DIM   = 8;
constexpr long long P0 = 73856093, P1 = 19349669, P2 = 83492791;

typedef float vf4 __attribute__((ext_vector_type(4)));

__global__ __launch_bounds__(256) void nvh_kernel(
    const float* __restrict__ qp,
    const float* __restrict__ feats,
    const int* __restrict__ idx_tab,
    float* __restrict__ out, int n)
{
    int i = blockIdx.x * blockDim.x + threadIdx.x;
    if (i >= n) return;

    const float px = qp[3 * i + 0];
    const float py = qp[3 * i + 1];
    const float pz = qp[3 * i + 2];

    const float resv[3] = {0.3f, 0.6f, 1.2f};

    // ---- Phase 1: hashes for all 3 levels; issue all 24 index loads in one batch.
    float dxv[3], dyv[3], dzv[3];
    int idxv[3][8];
#pragma unroll
    for (int lvl = 0; lvl < 3; ++lvl) {
        const float res = resv[lvl];
        // IEEE f32 division to match JAX exactly (floor() boundary sensitivity)
        const float fx = px / res, fy = py / res, fz = pz / res;
        const float bx = floorf(fx), by = floorf(fy), bz = floorf(fz);
        dxv[lvl] = fx - bx; dyv[lvl] = fy - by; dzv[lvl] = fz - bz;

        const long long ix = (long long)bx;
        const long long iy = (long long)by;
        const long long iz = (long long)bz;

        // one 64-bit floor-mod per level; corner deltas are compile-time consts
        long long h0 = (ix * P0 + iy * P1 + iz * P2) % (long long)BUF;
        if (h0 < 0) h0 += BUF;
        const int k0 = (int)h0;  // [0, BUF)

        const int* tab = idx_tab + (long long)lvl * BUF;
#pragma unroll
        for (int c = 0; c < 8; ++c) {
            const long long offc = (((c >> 2) & 1) * P0 + ((c >> 1) & 1) * P1 +
                                    (c & 1) * P2) % (long long)BUF;  // const-folded
            int k = k0 + (int)offc;
            if (k >= BUF) k -= BUF;
            idxv[lvl][c] = tab[k];
        }
    }

    vf4 acc0 = (vf4)0.0f;
    vf4 acc1 = (vf4)0.0f;

    // ---- Phase 2: per level, batch-issue 16 non-temporal float4 feature loads,
    // then weight+accumulate. Fully unrolled so the scheduler can overlap levels.
#pragma unroll
    for (int lvl = 0; lvl < 3; ++lvl) {
        const float* fb = feats + (size_t)lvl * (size_t)NFEAT * DIM;

        bool valid = true;
        int id[8];
#pragma unroll
        for (int c = 0; c < 8; ++c) {
            valid = valid && (idxv[lvl][c] > -1);
            id[c] = idxv[lvl][c] > 0 ? idxv[lvl][c] : 0;  // max(idx, 0)
        }

        vf4 f[16];
#pragma unroll
        for (int c = 0; c < 8; ++c) {
            const vf4* fp = (const vf4*)(fb + (size_t)id[c] * DIM);
            f[2 * c + 0] = __builtin_nontemporal_load(fp + 0);
            f[2 * c + 1] = __builtin_nontemporal_load(fp + 1);
        }

        const float dx = dxv[lvl], dy = dyv[lvl], dz = dzv[lvl];
        const float wx1 = dx, wx0 = 1.0f - dx;
        const float wy1 = dy, wy0 = 1.0f - dy;
        const float wz1 = dz, wz0 = 1.0f - dz;

        vf4 lacc0 = (vf4)0.0f;
        vf4 lacc1 = (vf4)0.0f;
#pragma unroll
        for (int c = 0; c < 8; ++c) {
            const float wc = (((c >> 2) & 1) ? wx1 : wx0) *
                             (((c >> 1) & 1) ? wy1 : wy0) *
                             (((c     ) & 1) ? wz1 : wz0);
            lacc0 += wc * f[2 * c + 0];
            lacc1 += wc * f[2 * c + 1];
        }

        if (valid) { acc0 += lacc0; acc1 += lacc1; }
    }

    vf4* op = (vf4*)(out + (size_t)i * DIM);
    __builtin_nontemporal_store(acc0, op + 0);
    __builtin_nontemporal_store(acc1, op + 1);
}

extern "C" void kernel_launch(void* const* d_in, const int* in_sizes, int n_in,
                              void* d_out, int out_size, void* d_ws, size_t ws_size,
                              hipStream_t stream) {
    const float* qp      = (const float*)d_in[0];
    const float* feats   = (const float*)d_in[1];
    const int*   idx_tab = (const int*)d_in[2];
    float*       out     = (float*)d_out;

    const int n = in_sizes[0] / 3;
    const int block = 256;
    const int grid = (n + block - 1) / block;
    hipLaunchKernelGGL(nvh_kernel, dim3(grid), dim3(block), 0, stream,
                       qp, feats, idx_tab, out, n);
}

// Round 2
// 1333.994 us; speedup vs baseline: 1.0587x; 1.0384x over previous
//
#include <hip/hip_runtime.h>

// NeuralVoxelHash: out[i] = sum over 3 levels of trilinear-weighted gather of
// hashed voxel-corner features.
//
// inputs (harness delivers integer inputs as int32!):
//   d_in[0] query_points [1000000,3] f32
//   d_in[1] features     [3,4194304,8] f32
//   d_in[2] index_table  [3,5000000] int32  (reference int64, harness -> int)
// output: [1000000,8] f32
//
// Round-2 structure: FORCED load batching (round-1 post-mortem: VGPR=44 proved
// the compiler re-serialized the batches; sched_barrier(0) pins them).
//  - 24 index loads issued as one pinned batch.
//  - Per level, 16 feature float4 loads issued as one pinned batch; fine-grained
//    vmcnt waits then let FMAs overlap the drain.
//  - __launch_bounds__(256,4): cap VGPR at 128 (16 waves/CU — matches measured
//    occupancy today) so the batch can live in registers without halving waves.
//  - Feature loads / output stores nontemporal (protect 60 MB index tables in
//    L2/L3 from the 402 MB zero-reuse feature stream); index loads cached.
//  - Feature addresses as 32-bit voffsets ((unsigned)id*8 elems, <128 MB) so an
//    in-flight address costs 1 VGPR, keeping the 16-deep batch within budget.

constexpr int       BUF   = 5000000;
constexpr long long NFEAT = 4194304;
constexpr int       DIM   = 8;
constexpr long long P0 = 73856093, P1 = 19349669, P2 = 83492791;

typedef float vf4 __attribute__((ext_vector_type(4)));

__global__ __launch_bounds__(256, 4) void nvh_kernel(
    const float* __restrict__ qp,
    const float* __restrict__ feats,
    const int* __restrict__ idx_tab,
    float* __restrict__ out, int n)
{
    int i = blockIdx.x * blockDim.x + threadIdx.x;
    if (i >= n) return;

    const float px = qp[3 * i + 0];
    const float py = qp[3 * i + 1];
    const float pz = qp[3 * i + 2];

    const float resv[3] = {0.3f, 0.6f, 1.2f};

    // ---- Phase 1: hashes for all 3 levels; 24 index loads as ONE pinned batch.
    float dxv[3], dyv[3], dzv[3];
    int idxv[3][8];
#pragma unroll
    for (int lvl = 0; lvl < 3; ++lvl) {
        const float res = resv[lvl];
        // IEEE f32 division to match JAX exactly (floor() boundary sensitivity)
        const float fx = px / res, fy = py / res, fz = pz / res;
        const float bx = floorf(fx), by = floorf(fy), bz = floorf(fz);
        dxv[lvl] = fx - bx; dyv[lvl] = fy - by; dzv[lvl] = fz - bz;

        const long long ix = (long long)bx;
        const long long iy = (long long)by;
        const long long iz = (long long)bz;

        // one 64-bit floor-mod per level; corner deltas are compile-time consts
        long long h0 = (ix * P0 + iy * P1 + iz * P2) % (long long)BUF;
        if (h0 < 0) h0 += BUF;
        const int k0 = (int)h0;  // [0, BUF)

        const int* tab = idx_tab + (size_t)lvl * BUF;
#pragma unroll
        for (int c = 0; c < 8; ++c) {
            const long long offc = (((c >> 2) & 1) * P0 + ((c >> 1) & 1) * P1 +
                                    (c & 1) * P2) % (long long)BUF;  // const-folded
            int k = k0 + (int)offc;
            if (k >= BUF) k -= BUF;
            idxv[lvl][c] = tab[k];  // cached load: tables are the reusable 60 MB
        }
    }
    // Pin: all 24 index loads issue before anything below schedules above them.
    __builtin_amdgcn_sched_barrier(0);

    vf4 acc0 = (vf4)0.0f;
    vf4 acc1 = (vf4)0.0f;

    // ---- Phase 2: per level, pinned batch of 16 NT float4 feature loads,
    // then weight+accumulate (fine-grained vmcnt lets math overlap the drain).
#pragma unroll
    for (int lvl = 0; lvl < 3; ++lvl) {
        const float* fb = feats + (size_t)lvl * (size_t)NFEAT * DIM;

        bool valid = true;
        unsigned off[8];
#pragma unroll
        for (int c = 0; c < 8; ++c) {
            valid = valid && (idxv[lvl][c] > -1);
            const int id = idxv[lvl][c] > 0 ? idxv[lvl][c] : 0;  // max(idx, 0)
            off[c] = (unsigned)id * (unsigned)DIM;  // element offset, fits 32-bit
        }

        vf4 f[16];
#pragma unroll
        for (int c = 0; c < 8; ++c) {
            const vf4* fp = (const vf4*)(fb + off[c]);
            f[2 * c + 0] = __builtin_nontemporal_load(fp + 0);
            f[2 * c + 1] = __builtin_nontemporal_load(fp + 1);
        }
        // Pin: all 16 feature loads of this level are in flight before the math.
        __builtin_amdgcn_sched_barrier(0);

        const float dx = dxv[lvl], dy = dyv[lvl], dz = dzv[lvl];
        const float wx1 = dx, wx0 = 1.0f - dx;
        const float wy1 = dy, wy0 = 1.0f - dy;
        const float wz1 = dz, wz0 = 1.0f - dz;

        vf4 lacc0 = (vf4)0.0f;
        vf4 lacc1 = (vf4)0.0f;
#pragma unroll
        for (int c = 0; c < 8; ++c) {
            const float wc = (((c >> 2) & 1) ? wx1 : wx0) *
                             (((c >> 1) & 1) ? wy1 : wy0) *
                             (((c     ) & 1) ? wz1 : wz0);
            lacc0 += wc * f[2 * c + 0];
            lacc1 += wc * f[2 * c + 1];
        }

        if (valid) { acc0 += lacc0; acc1 += lacc1; }
    }

    vf4* op = (vf4*)(out + (size_t)i * DIM);
    __builtin_nontemporal_store(acc0, op + 0);
    __builtin_nontemporal_store(acc1, op + 1);
}

extern "C" void kernel_launch(void* const* d_in, const int* in_sizes, int n_in,
                              void* d_out, int out_size, void* d_ws, size_t ws_size,
                              hipStream_t stream) {
    const float* qp      = (const float*)d_in[0];
    const float* feats   = (const float*)d_in[1];
    const int*   idx_tab = (const int*)d_in[2];
    float*       out     = (float*)d_out;

    const int n = in_sizes[0] / 3;
    const int block = 256;
    const int grid = (n + block - 1) / block;
    hipLaunchKernelGGL(nvh_kernel, dim3(grid), dim3(block), 0, stream,
                       qp, feats, idx_tab, out, n);
}

// Round 3
// 1323.292 us; speedup vs baseline: 1.0673x; 1.0081x over previous
//
#include <hip/hip_runtime.h>

// NeuralVoxelHash: out[i] = sum over 3 levels of trilinear-weighted gather of
// hashed voxel-corner features.
//
// inputs (harness delivers integer inputs as int32!):
//   d_in[0] query_points [1000000,3] f32
//   d_in[1] features     [3,4194304,8] f32
//   d_in[2] index_table  [3,5000000] int32  (reference int64, harness -> int)
// output: [1000000,8] f32
//
// Round-3: FORCED 32-deep per-wave load pipeline via inline asm.
// Post-mortem r1/r2: source-level batching was re-serialized by the compiler
// both times (VGPR stayed 44/64 — a held 16x float4 batch alone needs 64).
// Queue-depth arithmetic: 6 TB/s at 128B/line x ~900ns latency needs ~260
// lines in flight per CU; we measured ~130 (3.4 TB/s plateau).
//  - Inline-asm global_load_dwordx4 with "=v" outputs: RA CANNOT shrink the
//    batch; 2 levels (32 loads) in flight per wave, counted s_waitcnt vmcnt(16)
//    + sched_barrier(0) (guide rule #18) between stages.
//  - SADDR form (SGPR base + 32-bit voffset, offset:16 imm): 1 VGPR per
//    in-flight address.
//  - __launch_bounds__(256,3): VGPR cap ~168 for the ~155-reg peak, 12 waves/CU.
//  - nt on feature loads + NT stores (protect index tables in L2/L3).

constexpr int       BUF   = 5000000;
constexpr long long NFEAT = 4194304;
constexpr int       DIM   = 8;
constexpr long long P0 = 73856093, P1 = 19349669, P2 = 83492791;

typedef float vf4 __attribute__((ext_vector_type(4)));

// 16B nontemporal gather: dst <- *(base + voff [+16]) , voff in bytes (32-bit)
#define GLD_NT0(dst, voff, base)                                   \
    asm volatile("global_load_dwordx4 %0, %1, %2 nt"               \
                 : "=v"(dst) : "v"(voff), "s"(base))
#define GLD_NT16(dst, voff, base)                                  \
    asm volatile("global_load_dwordx4 %0, %1, %2 offset:16 nt"     \
                 : "=v"(dst) : "v"(voff), "s"(base))

__global__ __launch_bounds__(256, 3) void nvh_kernel(
    const float* __restrict__ qp,
    const float* __restrict__ feats,
    const int* __restrict__ idx_tab,
    float* __restrict__ out, int n)
{
    int i = blockIdx.x * blockDim.x + threadIdx.x;
    if (i >= n) return;

    const float px = qp[3 * i + 0];
    const float py = qp[3 * i + 1];
    const float pz = qp[3 * i + 2];

    const float resv[3] = {0.3f, 0.6f, 1.2f};

    // ---- Phase 1: hashes for all 3 levels; 24 index loads as one batch.
    float dxv[3], dyv[3], dzv[3];
    int idxv[3][8];
#pragma unroll
    for (int lvl = 0; lvl < 3; ++lvl) {
        const float res = resv[lvl];
        // IEEE f32 division to match JAX exactly (floor() boundary sensitivity)
        const float fx = px / res, fy = py / res, fz = pz / res;
        const float bx = floorf(fx), by = floorf(fy), bz = floorf(fz);
        dxv[lvl] = fx - bx; dyv[lvl] = fy - by; dzv[lvl] = fz - bz;

        const long long ix = (long long)bx;
        const long long iy = (long long)by;
        const long long iz = (long long)bz;

        long long h0 = (ix * P0 + iy * P1 + iz * P2) % (long long)BUF;
        if (h0 < 0) h0 += BUF;
        const int k0 = (int)h0;  // [0, BUF)

        const int* tab = idx_tab + (size_t)lvl * BUF;
#pragma unroll
        for (int c = 0; c < 8; ++c) {
            const long long offc = (((c >> 2) & 1) * P0 + ((c >> 1) & 1) * P1 +
                                    (c & 1) * P2) % (long long)BUF;  // const-folded
            int k = k0 + (int)offc;
            if (k >= BUF) k -= BUF;
            idxv[lvl][c] = tab[k];  // cached: tables are the reusable 60 MB
        }
    }
    __builtin_amdgcn_sched_barrier(0);

    // ---- Byte offsets + validity masks for all levels (before any feature load
    // so L2's issue after L0-math has zero dependent work left).
    unsigned voff[3][8];
    float vm[3];
#pragma unroll
    for (int lvl = 0; lvl < 3; ++lvl) {
        bool valid = true;
#pragma unroll
        for (int c = 0; c < 8; ++c) {
            valid = valid && (idxv[lvl][c] > -1);
            const int id = idxv[lvl][c] > 0 ? idxv[lvl][c] : 0;  // max(idx, 0)
            voff[lvl][c] = (unsigned)id * 32u;  // byte offset, max 134 MB
        }
        vm[lvl] = valid ? 1.0f : 0.0f;
    }

    const float* fb0 = feats;
    const float* fb1 = feats + (size_t)1 * (size_t)NFEAT * DIM;
    const float* fb2 = feats + (size_t)2 * (size_t)NFEAT * DIM;

    vf4 f0[16], f1[16], f2[16];

    // ---- Issue L0 + L1 batches: 32 dwordx4 in flight per wave.
#pragma unroll
    for (int c = 0; c < 8; ++c) {
        GLD_NT0 (f0[2 * c + 0], voff[0][c], fb0);
        GLD_NT16(f0[2 * c + 1], voff[0][c], fb0);
    }
#pragma unroll
    for (int c = 0; c < 8; ++c) {
        GLD_NT0 (f1[2 * c + 0], voff[1][c], fb1);
        GLD_NT16(f1[2 * c + 1], voff[1][c], fb1);
    }

    vf4 acc0 = (vf4)0.0f;
    vf4 acc1 = (vf4)0.0f;

#define LEVEL_MATH(F, LVL)                                                  \
    do {                                                                    \
        const float dx = dxv[LVL], dy = dyv[LVL], dz = dzv[LVL];            \
        const float wx1 = dx, wx0 = 1.0f - dx;                              \
        const float wy1 = dy, wy0 = 1.0f - dy;                              \
        const float wz1 = dz, wz0 = 1.0f - dz;                              \
        vf4 lacc0 = (vf4)0.0f;                                              \
        vf4 lacc1 = (vf4)0.0f;                                              \
        _Pragma("unroll")                                                   \
        for (int c = 0; c < 8; ++c) {                                       \
            const float wc = (((c >> 2) & 1) ? wx1 : wx0) *                 \
                             (((c >> 1) & 1) ? wy1 : wy0) *                 \
                             (((c     ) & 1) ? wz1 : wz0);                  \
            lacc0 += wc * F[2 * c + 0];                                     \
            lacc1 += wc * F[2 * c + 1];                                     \
        }                                                                   \
        acc0 += vm[LVL] * lacc0;                                            \
        acc1 += vm[LVL] * lacc1;                                            \
    } while (0)

    // ---- Wait for L0 only (L1's 16 still in flight), do L0 math.
    asm volatile("s_waitcnt vmcnt(16)" ::: "memory");
    __builtin_amdgcn_sched_barrier(0);
    LEVEL_MATH(f0, 0);

    // ---- Issue L2 batch (now L1+L2 = 32 in flight again).
#pragma unroll
    for (int c = 0; c < 8; ++c) {
        GLD_NT0 (f2[2 * c + 0], voff[2][c], fb2);
        GLD_NT16(f2[2 * c + 1], voff[2][c], fb2);
    }

    // ---- Wait for L1 (L2 still in flight), math L1.
    asm volatile("s_waitcnt vmcnt(16)" ::: "memory");
    __builtin_amdgcn_sched_barrier(0);
    LEVEL_MATH(f1, 1);

    // ---- Drain L2, math L2.
    asm volatile("s_waitcnt vmcnt(0)" ::: "memory");
    __builtin_amdgcn_sched_barrier(0);
    LEVEL_MATH(f2, 2);

#undef LEVEL_MATH

    vf4* op = (vf4*)(out + (size_t)i * DIM);
    __builtin_nontemporal_store(acc0, op + 0);
    __builtin_nontemporal_store(acc1, op + 1);
}

extern "C" void kernel_launch(void* const* d_in, const int* in_sizes, int n_in,
                              void* d_out, int out_size, void* d_ws, size_t ws_size,
                              hipStream_t stream) {
    const float* qp      = (const float*)d_in[0];
    const float* feats   = (const float*)d_in[1];
    const int*   idx_tab = (const int*)d_in[2];
    float*       out     = (float*)d_out;

    const int n = in_sizes[0] / 3;
    const int block = 256;
    const int grid = (n + block - 1) / block;
    hipLaunchKernelGGL(nvh_kernel, dim3(grid), dim3(block), 0, stream,
                       qp, feats, idx_tab, out, n);
}

// Round 4
// 1258.138 us; speedup vs baseline: 1.1225x; 1.0518x over previous
//
#include <hip/hip_runtime.h>

// NeuralVoxelHash: out[i] = sum over 3 levels of trilinear-weighted gather of
// hashed voxel-corner features.
//
// inputs (harness delivers integer inputs as int32!):
//   d_in[0] query_points [1000000,3] f32
//   d_in[1] features     [3,4194304,8] f32
//   d_in[2] index_table  [3,5000000] int32  (reference int64, harness -> int)
// output: [1000000,8] f32
//
// Round-4: LEVEL-PHASED execution for Infinity-Cache residency.
// Post-mortem r1-r3: three different load schedules all plateau at 3.4-3.55
// TB/s of L2-miss traffic -> queue depth is not the limiter. Reuse analysis:
// per level, 8M gathers touch only ~1.03M distinct 128B feature lines
// (132 MB, ~7.8 touches/line). Per-level working set (~195 MB incl. index
// table + qp + out) FITS the 256 MB L3; all-levels-at-once (396 MB) does not.
//  - 3 sequential dispatches, one level each: pass 0 writes out, passes 1-2
//    accumulate (same FP association as reference: ((l0)+l1)+l2).
//  - NO nontemporal hints anywhere: we WANT features cached now (r1-r3's nt
//    told the caches to drop exactly the lines with 7.8x reuse).
//  - Keep forced 16-deep feature-load batch (inline asm, SGPR base + 32-bit
//    voffset) to cover L3-hit latency; __launch_bounds__(256,4).

constexpr int       BUF   = 5000000;
constexpr long long NFEAT = 4194304;
constexpr int       DIM   = 8;
constexpr long long P0 = 73856093, P1 = 19349669, P2 = 83492791;

typedef float vf4 __attribute__((ext_vector_type(4)));

// 16B gather (cached): dst <- *(base + voff [+16]); voff = 32-bit byte offset
#define GLD0(dst, voff, base)                                  \
    asm volatile("global_load_dwordx4 %0, %1, %2"              \
                 : "=v"(dst) : "v"(voff), "s"(base))
#define GLD16(dst, voff, base)                                 \
    asm volatile("global_load_dwordx4 %0, %1, %2 offset:16"    \
                 : "=v"(dst) : "v"(voff), "s"(base))

template <bool ADD>
__global__ __launch_bounds__(256, 4) void nvh_level_kernel(
    const float* __restrict__ qp,
    const float* __restrict__ fb,    // this level's feature table base
    const int* __restrict__ tab,     // this level's index table base
    float* __restrict__ out, int n, float res)
{
    int i = blockIdx.x * blockDim.x + threadIdx.x;
    if (i >= n) return;

    const float px = qp[3 * i + 0];
    const float py = qp[3 * i + 1];
    const float pz = qp[3 * i + 2];

    // IEEE f32 division to match JAX exactly (floor() boundary sensitivity)
    const float fx = px / res, fy = py / res, fz = pz / res;
    const float bx = floorf(fx), by = floorf(fy), bz = floorf(fz);
    const float dx = fx - bx, dy = fy - by, dz = fz - bz;

    const long long ix = (long long)bx;
    const long long iy = (long long)by;
    const long long iz = (long long)bz;

    // one 64-bit floor-mod; corner deltas are compile-time consts
    long long h0 = (ix * P0 + iy * P1 + iz * P2) % (long long)BUF;
    if (h0 < 0) h0 += BUF;
    const int k0 = (int)h0;  // [0, BUF)

    // ---- 8 index gathers as one batch (table: 20 MB, L3-resident this pass).
    int idxv[8];
#pragma unroll
    for (int c = 0; c < 8; ++c) {
        const long long offc = (((c >> 2) & 1) * P0 + ((c >> 1) & 1) * P1 +
                                (c & 1) * P2) % (long long)BUF;  // const-folded
        int k = k0 + (int)offc;
        if (k >= BUF) k -= BUF;
        idxv[c] = tab[k];
    }
    __builtin_amdgcn_sched_barrier(0);

    bool valid = true;
    unsigned voff[8];
#pragma unroll
    for (int c = 0; c < 8; ++c) {
        valid = valid && (idxv[c] > -1);
        const int id = idxv[c] > 0 ? idxv[c] : 0;  // max(idx, 0)
        voff[c] = (unsigned)id * 32u;              // byte offset, < 2^27
    }

    // ---- 16 feature float4 loads issued as one forced batch (cached).
    vf4 f[16];
#pragma unroll
    for (int c = 0; c < 8; ++c) {
        GLD0 (f[2 * c + 0], voff[c], fb);
        GLD16(f[2 * c + 1], voff[c], fb);
    }

    // Accumulation input: issue while the 16 gathers are in flight.
    vf4 prev0, prev1;
    if (ADD) {
        const vf4* op = (const vf4*)(out + (size_t)i * DIM);
        prev0 = op[0];
        prev1 = op[1];
    }

    const float wx1 = dx, wx0 = 1.0f - dx;
    const float wy1 = dy, wy0 = 1.0f - dy;
    const float wz1 = dz, wz0 = 1.0f - dz;
    const float vmask = valid ? 1.0f : 0.0f;

    asm volatile("s_waitcnt vmcnt(0)" ::: "memory");
    __builtin_amdgcn_sched_barrier(0);

    vf4 lacc0 = (vf4)0.0f;
    vf4 lacc1 = (vf4)0.0f;
#pragma unroll
    for (int c = 0; c < 8; ++c) {
        const float wc = (((c >> 2) & 1) ? wx1 : wx0) *
                         (((c >> 1) & 1) ? wy1 : wy0) *
                         (((c     ) & 1) ? wz1 : wz0);
        lacc0 += wc * f[2 * c + 0];
        lacc1 += wc * f[2 * c + 1];
    }

    vf4 r0 = vmask * lacc0;
    vf4 r1 = vmask * lacc1;
    if (ADD) { r0 += prev0; r1 += prev1; }

    vf4* op = (vf4*)(out + (size_t)i * DIM);
    op[0] = r0;
    op[1] = r1;
}

extern "C" void kernel_launch(void* const* d_in, const int* in_sizes, int n_in,
                              void* d_out, int out_size, void* d_ws, size_t ws_size,
                              hipStream_t stream) {
    const float* qp      = (const float*)d_in[0];
    const float* feats   = (const float*)d_in[1];
    const int*   idx_tab = (const int*)d_in[2];
    float*       out     = (float*)d_out;

    const int n = in_sizes[0] / 3;
    const int block = 256;
    const int grid = (n + block - 1) / block;

    // One dispatch per level: at any instant the device hammers ONE level's
    // ~195 MB working set, which is L3-resident. Stream order serializes.
    hipLaunchKernelGGL((nvh_level_kernel<false>), dim3(grid), dim3(block), 0,
                       stream, qp, feats, idx_tab, out, n, 0.3f);
    hipLaunchKernelGGL((nvh_level_kernel<true>), dim3(grid), dim3(block), 0,
                       stream, qp, feats + (size_t)1 * NFEAT * DIM,
                       idx_tab + (size_t)1 * BUF, out, n, 0.6f);
    hipLaunchKernelGGL((nvh_level_kernel<true>), dim3(grid), dim3(block), 0,
                       stream, qp, feats + (size_t)2 * NFEAT * DIM,
                       idx_tab + (size_t)2 * BUF, out, n, 1.2f);
}

// Round 5
// 1099.176 us; speedup vs baseline: 1.2849x; 1.1446x over previous
//
#include <hip/hip_runtime.h>

// NeuralVoxelHash: out[i] = sum over 3 levels of trilinear-weighted gather of
// hashed voxel-corner features.
//
// inputs (harness delivers integer inputs as int32!):
//   d_in[0] query_points [1000000,3] f32
//   d_in[1] features     [3,4194304,8] f32
//   d_in[2] index_table  [3,5000000] int32  (reference int64, harness -> int)
// output: [1000000,8] f32
//
// Round-5: SPATIAL SORT to reduce L2-miss request count.
// Post-mortem r0-r4: five schedules (occupancy 31-54%, ILP 8-32 deep, nt vs
// cached, phased vs fused) all pin at 3.4-3.55 TB/s of L2-miss traffic with
// ~0% L2 hit rate on feature gathers (FETCH == 8M x 128B per pass). That is a
// line-fill request-rate ceiling; the only lever left is FEWER misses.
// Points in the same voxel cell share all 8 corner rows, but random point
// order never puts them in the same wave. Fix: counting-sort points by
// 21-bit Morton key of their level-2 cell; same-cell points become
// wave-adjacent -> identical corner addresses merge in the coalescer / hit L1.
// Expected multiplicity (Gaussian sigma=25): ~2-3x at level 2, ~1.3x level 1.
// Per-point math untouched -> bitwise-identical output (atomic within-bin
// order only permutes processing, not results).
//
// ws layout: hist[2M u32] | bsum[2048 u32] | keys[n u32] | perm[n u32] |
//            invp[n u32] | qps[n*3 f32] | out_s[n*8 f32]   (~64.5 MB)
// Falls back to round-4 direct path if ws is too small.

constexpr int       BUF   = 5000000;
constexpr long long NFEAT = 4194304;
constexpr int       DIM   = 8;
constexpr long long P0 = 73856093, P1 = 19349669, P2 = 83492791;
constexpr int       NBINS = 1 << 21;   // 7 bits/axis Morton

typedef float vf4 __attribute__((ext_vector_type(4)));

// 16B gather (cached): dst <- *(base + voff [+16]); voff = 32-bit byte offset
#define GLD0(dst, voff, base)                                  \
    asm volatile("global_load_dwordx4 %0, %1, %2"              \
                 : "=v"(dst) : "v"(voff), "s"(base))
#define GLD16(dst, voff, base)                                 \
    asm volatile("global_load_dwordx4 %0, %1, %2 offset:16"    \
                 : "=v"(dst) : "v"(voff), "s"(base))

// ---------------- level kernel (same math as round 4, param'd in/out) -------
template <bool ADD>
__global__ __launch_bounds__(256, 4) void nvh_level_kernel(
    const float* __restrict__ in,    // points, [n,3] (sorted or raw)
    const float* __restrict__ fb,    // this level's feature table base
    const int* __restrict__ tab,     // this level's index table base
    float* __restrict__ outp,        // [n,8] (sorted or raw)
    int n, float res)
{
    int i = blockIdx.x * blockDim.x + threadIdx.x;
    if (i >= n) return;

    const float px = in[3 * i + 0];
    const float py = in[3 * i + 1];
    const float pz = in[3 * i + 2];

    // IEEE f32 division to match JAX exactly (floor() boundary sensitivity)
    const float fx = px / res, fy = py / res, fz = pz / res;
    const float bx = floorf(fx), by = floorf(fy), bz = floorf(fz);
    const float dx = fx - bx, dy = fy - by, dz = fz - bz;

    const long long ix = (long long)bx;
    const long long iy = (long long)by;
    const long long iz = (long long)bz;

    long long h0 = (ix * P0 + iy * P1 + iz * P2) % (long long)BUF;
    if (h0 < 0) h0 += BUF;
    const int k0 = (int)h0;  // [0, BUF)

    int idxv[8];
#pragma unroll
    for (int c = 0; c < 8; ++c) {
        const long long offc = (((c >> 2) & 1) * P0 + ((c >> 1) & 1) * P1 +
                                (c & 1) * P2) % (long long)BUF;  // const-folded
        int k = k0 + (int)offc;
        if (k >= BUF) k -= BUF;
        idxv[c] = tab[k];
    }
    __builtin_amdgcn_sched_barrier(0);

    bool valid = true;
    unsigned voff[8];
#pragma unroll
    for (int c = 0; c < 8; ++c) {
        valid = valid && (idxv[c] > -1);
        const int id = idxv[c] > 0 ? idxv[c] : 0;  // max(idx, 0)
        voff[c] = (unsigned)id * 32u;              // byte offset, < 2^27
    }

    vf4 f[16];
#pragma unroll
    for (int c = 0; c < 8; ++c) {
        GLD0 (f[2 * c + 0], voff[c], fb);
        GLD16(f[2 * c + 1], voff[c], fb);
    }

    vf4 prev0, prev1;
    if (ADD) {
        const vf4* op = (const vf4*)(outp + (size_t)i * DIM);
        prev0 = op[0];
        prev1 = op[1];
    }

    const float wx1 = dx, wx0 = 1.0f - dx;
    const float wy1 = dy, wy0 = 1.0f - dy;
    const float wz1 = dz, wz0 = 1.0f - dz;
    const float vmask = valid ? 1.0f : 0.0f;

    asm volatile("s_waitcnt vmcnt(0)" ::: "memory");
    __builtin_amdgcn_sched_barrier(0);

    vf4 lacc0 = (vf4)0.0f;
    vf4 lacc1 = (vf4)0.0f;
#pragma unroll
    for (int c = 0; c < 8; ++c) {
        const float wc = (((c >> 2) & 1) ? wx1 : wx0) *
                         (((c >> 1) & 1) ? wy1 : wy0) *
                         (((c     ) & 1) ? wz1 : wz0);
        lacc0 += wc * f[2 * c + 0];
        lacc1 += wc * f[2 * c + 1];
    }

    vf4 r0 = vmask * lacc0;
    vf4 r1 = vmask * lacc1;
    if (ADD) { r0 += prev0; r1 += prev1; }

    vf4* op = (vf4*)(outp + (size_t)i * DIM);
    op[0] = r0;
    op[1] = r1;
}

// ---------------- sort machinery --------------------------------------------
__device__ __forceinline__ unsigned spread3(unsigned v) {
    // classic 10-bit Morton spread (covers our 7 bits)
    v = (v | (v << 16)) & 0x030000FFu;
    v = (v | (v << 8))  & 0x0300F00Fu;
    v = (v | (v << 4))  & 0x030C30C3u;
    v = (v | (v << 2))  & 0x09249249u;
    return v;
}

__global__ __launch_bounds__(256) void zero_hist(unsigned* __restrict__ h) {
    int i = blockIdx.x * blockDim.x + threadIdx.x;
    for (int k = i; k < NBINS; k += gridDim.x * blockDim.x) h[k] = 0u;
}

__global__ __launch_bounds__(256) void keys_hist(
    const float* __restrict__ qp, unsigned* __restrict__ keys,
    unsigned* __restrict__ hist, int n)
{
    int i = blockIdx.x * blockDim.x + threadIdx.x;
    if (i >= n) return;
    const float inv = 1.0f / 1.2f;   // level-2 cell (sort key only; any binning ok)
    int cx = (int)floorf(qp[3 * i + 0] * inv);
    int cy = (int)floorf(qp[3 * i + 1] * inv);
    int cz = (int)floorf(qp[3 * i + 2] * inv);
    cx = cx < -64 ? -64 : (cx > 63 ? 63 : cx);
    cy = cy < -64 ? -64 : (cy > 63 ? 63 : cy);
    cz = cz < -64 ? -64 : (cz > 63 ? 63 : cz);
    const unsigned key = (spread3((unsigned)(cx + 64)) << 2) |
                         (spread3((unsigned)(cy + 64)) << 1) |
                          spread3((unsigned)(cz + 64));
    keys[i] = key;
    atomicAdd(&hist[key], 1u);
}

// block-level exclusive scan: 2048 blocks x 1024 elems (256 thr x 4)
__global__ __launch_bounds__(256) void scan_blocks(
    unsigned* __restrict__ data, unsigned* __restrict__ bsum)
{
    __shared__ unsigned s[256];
    const int t = threadIdx.x;
    const int base = blockIdx.x * 1024 + t * 4;
    unsigned v0 = data[base + 0], v1 = data[base + 1];
    unsigned v2 = data[base + 2], v3 = data[base + 3];
    const unsigned tsum = v0 + v1 + v2 + v3;
    s[t] = tsum;
    __syncthreads();
    for (int off = 1; off < 256; off <<= 1) {
        unsigned x = (t >= off) ? s[t - off] : 0u;
        __syncthreads();
        s[t] += x;
        __syncthreads();
    }
    const unsigned excl = s[t] - tsum;
    if (t == 255) bsum[blockIdx.x] = s[255];
    data[base + 0] = excl;
    data[base + 1] = excl + v0;
    data[base + 2] = excl + v0 + v1;
    data[base + 3] = excl + v0 + v1 + v2;
}

// single-block exclusive scan of the 2048 block sums (256 thr x 8)
__global__ __launch_bounds__(256) void scan_top(unsigned* __restrict__ bsum) {
    __shared__ unsigned s[256];
    const int t = threadIdx.x;
    unsigned v[8];
    unsigned tsum = 0;
#pragma unroll
    for (int j = 0; j < 8; ++j) { v[j] = bsum[t * 8 + j]; tsum += v[j]; }
    s[t] = tsum;
    __syncthreads();
    for (int off = 1; off < 256; off <<= 1) {
        unsigned x = (t >= off) ? s[t - off] : 0u;
        __syncthreads();
        s[t] += x;
        __syncthreads();
    }
    unsigned run = s[t] - tsum;
#pragma unroll
    for (int j = 0; j < 8; ++j) { const unsigned nv = run; run += v[j]; bsum[t * 8 + j] = nv; }
}

__global__ __launch_bounds__(256) void scan_add(
    unsigned* __restrict__ data, const unsigned* __restrict__ bsum)
{
    const int base = blockIdx.x * 1024 + threadIdx.x * 4;
    const unsigned add = bsum[blockIdx.x];
    data[base + 0] += add;
    data[base + 1] += add;
    data[base + 2] += add;
    data[base + 3] += add;
}

__global__ __launch_bounds__(256) void scatter_perm(
    const unsigned* __restrict__ keys, unsigned* __restrict__ hist,
    unsigned* __restrict__ perm, unsigned* __restrict__ invp, int n)
{
    int i = blockIdx.x * blockDim.x + threadIdx.x;
    if (i >= n) return;
    const unsigned r = atomicAdd(&hist[keys[i]], 1u);
    perm[r] = (unsigned)i;
    invp[i] = r;
}

__global__ __launch_bounds__(256) void gather_points(
    const float* __restrict__ qp, const unsigned* __restrict__ perm,
    float* __restrict__ qps, int n)
{
    int i = blockIdx.x * blockDim.x + threadIdx.x;
    if (i >= n) return;
    const unsigned j = perm[i];          // qp is 12 MB: gather hits L2/L3
    qps[3 * i + 0] = qp[3 * j + 0];
    qps[3 * i + 1] = qp[3 * j + 1];
    qps[3 * i + 2] = qp[3 * j + 2];
}

__global__ __launch_bounds__(256) void unpermute_out(
    const float* __restrict__ out_s, const unsigned* __restrict__ invp,
    float* __restrict__ out, int n)
{
    int i = blockIdx.x * blockDim.x + threadIdx.x;
    if (i >= n) return;
    const unsigned r = invp[i];          // out_s is 32 MB: gather mostly L2/L3
    const vf4* a = (const vf4*)(out_s + (size_t)r * DIM);
    const vf4 x = a[0], y = a[1];
    vf4* o = (vf4*)(out + (size_t)i * DIM);
    o[0] = x;
    o[1] = y;
}

// ---------------- launch ----------------------------------------------------
extern "C" void kernel_launch(void* const* d_in, const int* in_sizes, int n_in,
                              void* d_out, int out_size, void* d_ws, size_t ws_size,
                              hipStream_t stream) {
    const float* qp      = (const float*)d_in[0];
    const float* feats   = (const float*)d_in[1];
    const int*   idx_tab = (const int*)d_in[2];
    float*       out     = (float*)d_out;

    const int n = in_sizes[0] / 3;
    const int block = 256;
    const int grid = (n + block - 1) / block;

    auto al = [](size_t x) { return (x + 255) & ~(size_t)255; };
    const size_t o_hist = 0;
    const size_t o_bsum = al(o_hist + (size_t)NBINS * 4);
    const size_t o_keys = al(o_bsum + 2048 * 4);
    const size_t o_perm = al(o_keys + (size_t)n * 4);
    const size_t o_invp = al(o_perm + (size_t)n * 4);
    const size_t o_qps  = al(o_invp + (size_t)n * 4);
    const size_t o_outs = al(o_qps  + (size_t)n * 12);
    const size_t need   = o_outs + (size_t)n * 32;

    const bool use_sort = (d_ws != nullptr) && (ws_size >= need);

    const float* in_pts = qp;
    float*       out_l  = out;

    if (use_sort) {
        char* ws = (char*)d_ws;
        unsigned* hist = (unsigned*)(ws + o_hist);
        unsigned* bsum = (unsigned*)(ws + o_bsum);
        unsigned* keys = (unsigned*)(ws + o_keys);
        unsigned* perm = (unsigned*)(ws + o_perm);
        unsigned* invp = (unsigned*)(ws + o_invp);
        float*    qps  = (float*)   (ws + o_qps);
        float*    outs = (float*)   (ws + o_outs);

        hipLaunchKernelGGL(zero_hist, dim3(2048), dim3(block), 0, stream, hist);
        hipLaunchKernelGGL(keys_hist, dim3(grid), dim3(block), 0, stream,
                           qp, keys, hist, n);
        hipLaunchKernelGGL(scan_blocks, dim3(NBINS / 1024), dim3(block), 0,
                           stream, hist, bsum);
        hipLaunchKernelGGL(scan_top, dim3(1), dim3(block), 0, stream, bsum);
        hipLaunchKernelGGL(scan_add, dim3(NBINS / 1024), dim3(block), 0,
                           stream, hist, bsum);
        hipLaunchKernelGGL(scatter_perm, dim3(grid), dim3(block), 0, stream,
                           keys, hist, perm, invp, n);
        hipLaunchKernelGGL(gather_points, dim3(grid), dim3(block), 0, stream,
                           qp, perm, qps, n);

        in_pts = qps;
        out_l  = outs;

        hipLaunchKernelGGL((nvh_level_kernel<false>), dim3(grid), dim3(block),
                           0, stream, in_pts, feats, idx_tab, out_l, n, 0.3f);
        hipLaunchKernelGGL((nvh_level_kernel<true>), dim3(grid), dim3(block),
                           0, stream, in_pts, feats + (size_t)1 * NFEAT * DIM,
                           idx_tab + (size_t)1 * BUF, out_l, n, 0.6f);
        hipLaunchKernelGGL((nvh_level_kernel<true>), dim3(grid), dim3(block),
                           0, stream, in_pts, feats + (size_t)2 * NFEAT * DIM,
                           idx_tab + (size_t)2 * BUF, out_l, n, 1.2f);

        hipLaunchKernelGGL(unpermute_out, dim3(grid), dim3(block), 0, stream,
                           outs, invp, out, n);
    } else {
        // fallback: round-4 behavior (unsorted, direct out)
        hipLaunchKernelGGL((nvh_level_kernel<false>), dim3(grid), dim3(block),
                           0, stream, qp, feats, idx_tab, out, n, 0.3f);
        hipLaunchKernelGGL((nvh_level_kernel<true>), dim3(grid), dim3(block),
                           0, stream, qp, feats + (size_t)1 * NFEAT * DIM,
                           idx_tab + (size_t)1 * BUF, out, n, 0.6f);
        hipLaunchKernelGGL((nvh_level_kernel<true>), dim3(grid), dim3(block),
                           0, stream, qp, feats + (size_t)2 * NFEAT * DIM,
                           idx_tab + (size_t)2 * BUF, out, n, 1.2f);
    }
}